// Round 2
// baseline (557.637 us; speedup 1.0000x reference)
//
#include <hip/hip_runtime.h>

typedef _Float16 f16;
typedef _Float16 f16x8 __attribute__((ext_vector_type(8)));
typedef float f32x16 __attribute__((ext_vector_type(16)));

#define MFMA32(A, B, C) __builtin_amdgcn_mfma_f32_32x32x16_f16((A), (B), (C), 0, 0, 0)

__device__ __forceinline__ float sigm_(float x) {
    return __builtin_amdgcn_rcpf(1.f + __builtin_amdgcn_exp2f(-1.44269504088896f * x));
}
__device__ __forceinline__ float tanh_(float x) {
    float e = __builtin_amdgcn_exp2f(2.88539008177793f * x);   // e^(2x)
    return 1.f - 2.f * __builtin_amdgcn_rcpf(1.f + e);
}

// Convert a row-major fp32 weight W[J][256] into fragment-major f16 for
// v_mfma_f32_32x32x16_f16 B-operand (B[k][j] = W[j][k]):
// idx = ((nt*16 + kt)*64 + lane)*8 + e ;  j = nt*32 + (lane&31), k = kt*16 + (lane>>5)*8 + e
__global__ void frag_conv(const float* __restrict__ W, f16* __restrict__ dst, int total) {
    for (int idx = blockIdx.x * blockDim.x + threadIdx.x; idx < total;
         idx += gridDim.x * blockDim.x) {
        int e  = idx & 7;
        int lp = (idx >> 3) & 63;
        int kt = (idx >> 9) & 15;
        int nt = idx >> 13;
        int j = (nt << 5) + (lp & 31);
        int k = (kt << 4) + ((lp >> 5) << 3) + e;
        dst[idx] = (f16)W[j * 256 + k];
    }
}

__global__ __launch_bounds__(512)
void lstm_fused(const float* __restrict__ statf,   // [8192][256]
                const float* __restrict__ tfg,     // [8192][24]
                const float* __restrict__ tmg,     // [8192][24]
                const float* __restrict__ h0,      // [8192][256]
                const float* __restrict__ c0,      // [8192][256]
                const float* __restrict__ Wih,     // [1024][2]
                const float* __restrict__ bih,     // [1024]
                const float* __restrict__ bhh,     // [1024]
                const float* __restrict__ b1,
                const float* __restrict__ b2,
                const float* __restrict__ b3,
                const float* __restrict__ Wlr,     // [512]
                const float* __restrict__ blr,     // [1]
                const f16* __restrict__ WBH,       // frag-major W_hh  (32 nt)
                const f16* __restrict__ WB1,       // frag-major W1    (8 nt)
                const f16* __restrict__ WB2,
                const f16* __restrict__ WB3,
                float* __restrict__ out)           // [8193]
{
    // A-fragment layout LDS: Af[buf][kt][lane][e] <-> val[row=lane&31][k=kt*16+(lane>>5)*8+e]
    __shared__ f16   Af[3][16][64][8];   // 48 KB: buf0/1 = h ping-pong, buf2 = static/s
    __shared__ float tf_l[32][24];
    __shared__ float tm_l[32][24];
    __shared__ float wlr_l[512];

    const int tid = threadIdx.x;
    const int w   = tid >> 6;       // wave 0..7
    const int l   = tid & 63;       // lane
    const int b0  = blockIdx.x * 32;

    // ---------------- init fills ----------------
    for (int i = tid; i < 32 * 24; i += 512) {
        int r = i / 24, t = i - r * 24;
        tf_l[r][t] = tfg[(b0 + r) * 24 + t];
        tm_l[r][t] = tmg[(b0 + r) * 24 + t];
    }
    wlr_l[tid] = Wlr[tid];

    // h0 -> Af[0], static -> Af[2]
    for (int i = tid; i < 1024; i += 512) {
        int fr = i >> 6, lp = i & 63;
        int row  = lp & 31;
        int koff = (fr << 4) + ((lp >> 5) << 3);
        const float4* s4 = (const float4*)&h0[(b0 + row) * 256 + koff];
        float4 a = s4[0], b = s4[1];
        f16x8 v;
        v[0]=(f16)a.x; v[1]=(f16)a.y; v[2]=(f16)a.z; v[3]=(f16)a.w;
        v[4]=(f16)b.x; v[5]=(f16)b.y; v[6]=(f16)b.z; v[7]=(f16)b.w;
        *(f16x8*)(&Af[0][fr][lp][0]) = v;
        const float4* t4 = (const float4*)&statf[(b0 + row) * 256 + koff];
        float4 c = t4[0], d = t4[1];
        f16x8 v2;
        v2[0]=(f16)c.x; v2[1]=(f16)c.y; v2[2]=(f16)c.z; v2[3]=(f16)c.w;
        v2[4]=(f16)d.x; v2[5]=(f16)d.y; v2[6]=(f16)d.z; v2[7]=(f16)d.w;
        *(f16x8*)(&Af[2][fr][lp][0]) = v2;
    }

    // ---------------- per-lane constants ----------------
    const int jc = (w << 5) + (l & 31);          // this lane's h-column (0..255)
    float xa[4], xb[4], xc[4];
    #pragma unroll
    for (int g = 0; g < 4; ++g) {
        int jj = (g << 8) + jc;
        xa[g] = Wih[jj * 2];
        xb[g] = Wih[jj * 2 + 1];
        xc[g] = bih[jj] + bhh[jj];
    }
    float cst[16];
    #pragma unroll
    for (int reg = 0; reg < 16; ++reg) {
        int bl = (reg & 3) + ((reg >> 2) << 3) + ((l >> 5) << 2);
        cst[reg] = c0[(b0 + bl) * 256 + jc];
    }
    __syncthreads();

    const int lane8   = l << 3;
    const int wkt     = jc >> 4;                  // kt this lane writes (h scatter)
    const int wlp_hi  = ((l >> 3) & 1) << 5;
    const int we      = l & 7;

    // ---------------- LSTM over 24 steps ----------------
    #pragma unroll 1
    for (int t = 0; t < 24; ++t) {
        const int cur = t & 1;
        f32x16 acc[4];
        #pragma unroll
        for (int g = 0; g < 4; ++g)
            #pragma unroll
            for (int e = 0; e < 16; ++e) acc[g][e] = xc[g];   // fold bias into C

        f16x8 Bf[2][4];
        f16x8 Aq[2];
        #pragma unroll
        for (int g = 0; g < 4; ++g)
            Bf[0][g] = *(const f16x8*)(WBH + (((g * 8 + w) * 16 + 0) * 512) + lane8);
        Aq[0] = *(const f16x8*)(&Af[cur][0][l][0]);

        #pragma unroll
        for (int kt = 0; kt < 16; ++kt) {
            const int cb = kt & 1, nb = cb ^ 1;
            if (kt < 15) {
                #pragma unroll
                for (int g = 0; g < 4; ++g)
                    Bf[nb][g] = *(const f16x8*)(WBH + (((g * 8 + w) * 16 + (kt + 1)) * 512) + lane8);
                Aq[nb] = *(const f16x8*)(&Af[cur][kt + 1][l][0]);
            }
            #pragma unroll
            for (int g = 0; g < 4; ++g)
                acc[g] = MFMA32(Aq[cb], Bf[cb][g], acc[g]);
        }

        // epilogue: gates -> (c,h); write h (f16) into other A-frag buffer
        #pragma unroll
        for (int reg = 0; reg < 16; ++reg) {
            const int   bl  = (reg & 3) + ((reg >> 2) << 3) + ((l >> 5) << 2);
            const float tfv = tf_l[bl][t];
            const float tmv = tm_l[bl][t];
            float gi = acc[0][reg] + xa[0] * tfv + xb[0] * tmv;
            float gf = acc[1][reg] + xa[1] * tfv + xb[1] * tmv;
            float gg = acc[2][reg] + xa[2] * tfv + xb[2] * tmv;
            float go = acc[3][reg] + xa[3] * tfv + xb[3] * tmv;
            float i_ = sigm_(gi);
            float f_ = sigm_(gf);
            float g_ = tanh_(gg);
            float o_ = sigm_(go);
            float c_ = f_ * cst[reg] + i_ * g_;
            cst[reg] = c_;
            float h_ = o_ * tanh_(c_);
            Af[cur ^ 1][wkt][bl | wlp_hi][we] = (f16)h_;
        }
        __syncthreads();
    }
    // final h lives in Af[0]

    // ---------------- static MLP: 3 layers, in buf {2,1,2} -> out {1,2,1} ----------------
    {
        const f16*   WBl[3] = {WB1, WB2, WB3};
        const float* bls[3] = {b1, b2, b3};
        #pragma unroll
        for (int layer = 0; layer < 3; ++layer) {
            const int inb  = (layer == 1) ? 1 : 2;
            const int outb = (layer == 1) ? 2 : 1;
            float bias = bls[layer][jc];
            f32x16 acc2;
            #pragma unroll
            for (int e = 0; e < 16; ++e) acc2[e] = bias;

            f16x8 Bq[2], Aq2[2];
            Bq[0]  = *(const f16x8*)(WBl[layer] + ((w * 16 + 0) * 512) + lane8);
            Aq2[0] = *(const f16x8*)(&Af[inb][0][l][0]);
            #pragma unroll
            for (int kt = 0; kt < 16; ++kt) {
                const int cb = kt & 1, nb = cb ^ 1;
                if (kt < 15) {
                    Bq[nb]  = *(const f16x8*)(WBl[layer] + ((w * 16 + (kt + 1)) * 512) + lane8);
                    Aq2[nb] = *(const f16x8*)(&Af[inb][kt + 1][l][0]);
                }
                acc2 = MFMA32(Aq2[cb], Bq[cb], acc2);
            }
            #pragma unroll
            for (int reg = 0; reg < 16; ++reg) {
                float v = acc2[reg];
                v = v > 0.f ? v : 0.f;
                const int bl2 = (reg & 3) + ((reg >> 2) << 3) + ((l >> 5) << 2);
                Af[outb][wkt][bl2 | wlp_hi][we] = (f16)v;
            }
            __syncthreads();
        }
    }

    // ---------------- classifier: predicts = [h, s] . Wlr + blr ----------------
    {
        const int r  = (w << 2) + (l >> 4);     // row 0..31
        const int lg = l & 15;
        const int lp = r | (((lg >> 3) & 1) << 5);
        const int ee = lg & 7;
        float sum = 0.f;
        #pragma unroll
        for (int i = 0; i < 16; ++i) {
            int j = lg + (i << 4);
            float hv = (float)Af[0][i][lp][ee];
            float sv = (float)Af[1][i][lp][ee];
            sum += hv * wlr_l[j] + sv * wlr_l[256 + j];
        }
        sum += __shfl_xor(sum, 8);
        sum += __shfl_xor(sum, 4);
        sum += __shfl_xor(sum, 2);
        sum += __shfl_xor(sum, 1);
        if (lg == 0) out[b0 + r] = sum + blr[0];
    }
}

__global__ __launch_bounds__(1024)
void bce_kernel(const float* __restrict__ pred, const float* __restrict__ tgt,
                float* __restrict__ lossp) {
    const int tid = threadIdx.x;
    float acc = 0.f;
    for (int i = tid; i < 8192; i += 1024) {
        float p  = pred[i];
        float t  = tgt[i];
        float ax = fabsf(p);
        acc += fmaxf(p, 0.f) - p * t
             + log1pf(__builtin_amdgcn_exp2f(-1.44269504088896f * ax));
    }
    #pragma unroll
    for (int m = 32; m >= 1; m >>= 1) acc += __shfl_xor(acc, m);
    __shared__ float red[16];
    if ((tid & 63) == 0) red[tid >> 6] = acc;
    __syncthreads();
    if (tid < 16) {
        float v = red[tid];
        #pragma unroll
        for (int m = 8; m >= 1; m >>= 1) v += __shfl_xor(v, m);
        if (tid == 0) lossp[0] = v * (1.f / 8192.f);
    }
}

extern "C" void kernel_launch(void* const* d_in, const int* in_sizes, int n_in,
                              void* d_out, int out_size, void* d_ws, size_t ws_size,
                              hipStream_t stream) {
    const float* statf = (const float*)d_in[0];
    const float* tfg   = (const float*)d_in[1];
    const float* tmg   = (const float*)d_in[2];
    const float* tgt   = (const float*)d_in[3];
    const float* h0    = (const float*)d_in[4];
    const float* c0    = (const float*)d_in[5];
    const float* Wih   = (const float*)d_in[6];
    const float* Whh   = (const float*)d_in[7];
    const float* bih   = (const float*)d_in[8];
    const float* bhh   = (const float*)d_in[9];
    const float* W1    = (const float*)d_in[10];
    const float* b1    = (const float*)d_in[11];
    const float* W2    = (const float*)d_in[12];
    const float* b2    = (const float*)d_in[13];
    const float* W3    = (const float*)d_in[14];
    const float* b3    = (const float*)d_in[15];
    const float* Wlr   = (const float*)d_in[16];
    const float* blr   = (const float*)d_in[17];
    float* out = (float*)d_out;

    f16* WBH = (f16*)d_ws;            // 262144 halfs
    f16* WB1 = WBH + 262144;          // 65536 halfs each
    f16* WB2 = WB1 + 65536;
    f16* WB3 = WB2 + 65536;

    frag_conv<<<512, 512, 0, stream>>>(Whh, WBH, 262144);
    frag_conv<<<128, 512, 0, stream>>>(W1, WB1, 65536);
    frag_conv<<<128, 512, 0, stream>>>(W2, WB2, 65536);
    frag_conv<<<128, 512, 0, stream>>>(W3, WB3, 65536);

    lstm_fused<<<256, 512, 0, stream>>>(statf, tfg, tmg, h0, c0, Wih, bih, bhh,
                                        b1, b2, b3, Wlr, blr,
                                        WBH, WB1, WB2, WB3, out);

    bce_kernel<<<1, 1024, 0, stream>>>(out, tgt, out + 8192);
}